// Round 9
// baseline (192.102 us; speedup 1.0000x reference)
//
#include <hip/hip_runtime.h>
#include <hip/hip_bf16.h>
#include <stdint.h>

typedef short short8 __attribute__((ext_vector_type(8)));
typedef short short4v __attribute__((ext_vector_type(4)));
typedef float f32x4 __attribute__((ext_vector_type(4)));

__device__ __forceinline__ void gload16(const void* g, void* l) {
  __builtin_amdgcn_global_load_lds((const __attribute__((address_space(1))) void*)g,
                                   (__attribute__((address_space(3))) void*)l, 16, 0, 0);
}

__device__ __forceinline__ unsigned short f2b(float f) {
  unsigned int x = __float_as_uint(f);
  x += 0x7fffu + ((x >> 16) & 1u);
  return (unsigned short)(x >> 16);
}

// ==================== prep ====================
// [0,8192) cvt x->xb | [8192,9216) Wv->Wt2_V^T | [9216,9472) M^T=Wk.Wq^T |
// [9472,9504) sums=0 | [9504,13600) zero out rows>=1024 (atomic PV stripes)
__global__ __launch_bounds__(256) void prep(
    const float* __restrict__ x, const float* __restrict__ Wq,
    const float* __restrict__ Wk, const float* __restrict__ Wv,
    unsigned short* __restrict__ xb, unsigned short* __restrict__ Wt2,
    float* __restrict__ sums, float* __restrict__ out)
{
  __shared__ __align__(16) char smem[16384];
  const int bid = blockIdx.x;
  const int tid = threadIdx.x;
  if (bid < 8192) {
    const int i = bid * 256 + tid;
    const float4 f = ((const float4*)x)[i];
    union { unsigned short u[4]; uint2 v; } o;
    o.u[0] = f2b(f.x); o.u[1] = f2b(f.y); o.u[2] = f2b(f.z); o.u[3] = f2b(f.w);
    ((uint2*)xb)[i] = o.v;
  } else if (bid < 9216) {
    float (*tb)[33] = (float(*)[33])smem;
    const int t = bid - 8192;
    const int bx = t & 31, by = t >> 5;
    const int tx = tid & 31, ty = tid >> 5;
    const int xcol = bx * 32 + tx, y0 = by * 32;
    #pragma unroll
    for (int i = 0; i < 4; ++i)
      tb[ty + i * 8][tx] = Wv[(long long)(y0 + ty + i * 8) * 1024 + xcol];
    __syncthreads();
    unsigned short* O = Wt2 + 1024 * 1024;
    const int xo = by * 32 + tx, yo0 = bx * 32;
    #pragma unroll
    for (int i = 0; i < 4; ++i)
      O[(long long)(yo0 + ty + i * 8) * 1024 + xo] = f2b(tb[tx][ty + i * 8]);
  } else if (bid < 9472) {
    const int t = bid - 9216;
    const int bx = t & 15, by = t >> 4;
    const int row0 = by * 64, col0 = bx * 64;
    const int wave = tid >> 6, lane = tid & 63;
    const int wr = wave >> 1, wc = wave & 1;
    const int l15 = lane & 15, lk = lane >> 4;
    const int sr = lane >> 3, sg = lane & 7;
    char* lA = smem;
    char* lB = smem + 8192;
    const int rA = wr * 32 + l15, cB = wc * 32 + l15;
    const int xorA = (rA & 7) << 4, xorB = (cB & 7) << 4;
    const int kb = lk * 16;
    f32x4 acc[2][2];
    #pragma unroll
    for (int m = 0; m < 2; ++m)
      #pragma unroll
      for (int n = 0; n < 2; ++n) acc[m][n] = (f32x4)0.0f;
    for (int kt = 0; kt < 16; ++kt) {
      const int kc = kt * 64;
      short8 va[2], vb[2];
      int rr[2];
      #pragma unroll
      for (int j = 0; j < 2; ++j) {
        const int ci = wave * 2 + j;
        const int r = ci * 8 + sr;
        rr[j] = r;
        const float* pa = Wk + (long long)(row0 + r) * 1024 + kc + sg * 8;
        const float* pb = Wq + (long long)(col0 + r) * 1024 + kc + sg * 8;
        const float4 a0 = *(const float4*)pa, a1 = *(const float4*)(pa + 4);
        const float4 b0 = *(const float4*)pb, b1 = *(const float4*)(pb + 4);
        va[j][0] = (short)f2b(a0.x); va[j][1] = (short)f2b(a0.y);
        va[j][2] = (short)f2b(a0.z); va[j][3] = (short)f2b(a0.w);
        va[j][4] = (short)f2b(a1.x); va[j][5] = (short)f2b(a1.y);
        va[j][6] = (short)f2b(a1.z); va[j][7] = (short)f2b(a1.w);
        vb[j][0] = (short)f2b(b0.x); vb[j][1] = (short)f2b(b0.y);
        vb[j][2] = (short)f2b(b0.z); vb[j][3] = (short)f2b(b0.w);
        vb[j][4] = (short)f2b(b1.x); vb[j][5] = (short)f2b(b1.y);
        vb[j][6] = (short)f2b(b1.z); vb[j][7] = (short)f2b(b1.w);
      }
      __syncthreads();
      #pragma unroll
      for (int j = 0; j < 2; ++j) {
        const int off = rr[j] * 128 + ((sg * 16) ^ ((rr[j] & 7) << 4));
        *(short8*)(lA + off) = va[j];
        *(short8*)(lB + off) = vb[j];
      }
      __syncthreads();
      #pragma unroll
      for (int ks = 0; ks < 2; ++ks) {
        short8 af[2], bf[2];
        #pragma unroll
        for (int m = 0; m < 2; ++m)
          af[m] = *(const short8*)(lA + (rA + m * 16) * 128 + ((ks * 64 + kb) ^ xorA));
        #pragma unroll
        for (int n = 0; n < 2; ++n)
          bf[n] = *(const short8*)(lB + (cB + n * 16) * 128 + ((ks * 64 + kb) ^ xorB));
        #pragma unroll
        for (int m = 0; m < 2; ++m)
          #pragma unroll
          for (int n = 0; n < 2; ++n)
            acc[m][n] = __builtin_amdgcn_mfma_f32_16x16x32_bf16(af[m], bf[n], acc[m][n], 0, 0, 0);
      }
    }
    const int orow = row0 + wr * 32 + lk * 4;
    const int ocol = col0 + wc * 32 + l15;
    #pragma unroll
    for (int m = 0; m < 2; ++m)
      #pragma unroll
      for (int r = 0; r < 4; ++r)
        #pragma unroll
        for (int n = 0; n < 2; ++n)
          Wt2[(long long)(orow + m * 16 + r) * 1024 + ocol + n * 16] = f2b(acc[m][n][r]);
  } else if (bid < 9504) {
    const int i = (bid - 9472) * 256 + tid;
    sums[i] = 0.f;
  } else {
    // zero out[z][1024..2047][*] (16.8 MB), float4 per thread
    const long long i = (long long)(bid - 9504) * 256 + tid;
    const int z = (int)(i >> 18);
    const int r = (int)(i & 262143);
    float4* p = (float4*)(out + (long long)z * 2097152 + 1048576) + r;
    *p = make_float4(0.f, 0.f, 0.f, 0.f);
  }
}

// ==================== 256x256 8-phase GEMM (yv) ====================
#define STG(buf, isB, half, kt) do {                                           \
    const unsigned short* _s = (isB) ? Bz : Az;                                \
    const int _ld = (isB) ? ldb : lda;                                         \
    const int _b0 = (isB) ? col0 : row0;                                       \
    char* _d = lds + (buf) * 65536 + (isB) * 32768 + (half) * 16384;           \
    _Pragma("unroll")                                                          \
    for (int _i = 0; _i < 2; ++_i) {                                           \
      const int _c = wave * 2 + _i;                                            \
      const int _row = (half) * 128 + _c * 8 + srow;                           \
      gload16(_s + (long long)(_b0 + _row) * _ld + (kt) * 64 + sgrp * 8,       \
              _d + _c * 1024);                                                 \
    } } while (0)

#define LDA8(dst, buf, mh) do {                                                \
    _Pragma("unroll")                                                          \
    for (int _m = 0; _m < 4; ++_m) {                                           \
      const int _r = wr * 128 + ((mh) * 4 + _m) * 16 + (lane & 15);            \
      const char* _p = lds + (buf) * 65536 + _r * 128;                         \
      const int _x = (_r & 7) << 4;                                            \
      dst[_m][0] = *(const short8*)(_p + ((kbyte) ^ _x));                      \
      dst[_m][1] = *(const short8*)(_p + ((64 + kbyte) ^ _x));                 \
    } } while (0)

#define LDB4(dst, buf, nh) do {                                                \
    _Pragma("unroll")                                                          \
    for (int _n = 0; _n < 2; ++_n) {                                           \
      const int _r = wc * 64 + ((nh) * 2 + _n) * 16 + (lane & 15);             \
      const char* _p = lds + (buf) * 65536 + 32768 + _r * 128;                 \
      const int _x = (_r & 7) << 4;                                            \
      dst[_n][0] = *(const short8*)(_p + ((kbyte) ^ _x));                      \
      dst[_n][1] = *(const short8*)(_p + ((64 + kbyte) ^ _x));                 \
    } } while (0)

#define MFMA16(mh, nh, av, bv) do {                                            \
    __builtin_amdgcn_s_setprio(1);                                             \
    _Pragma("unroll") for (int _n = 0; _n < 2; ++_n)                           \
    _Pragma("unroll") for (int _m = 0; _m < 4; ++_m)                           \
    _Pragma("unroll") for (int _k = 0; _k < 2; ++_k)                           \
      acc[(mh)*4+_m][(nh)*2+_n] = __builtin_amdgcn_mfma_f32_16x16x32_bf16(     \
          av[_m][_k], bv[_n][_k], acc[(mh)*4+_m][(nh)*2+_n], 0, 0, 0);         \
    __builtin_amdgcn_s_setprio(0);                                             \
  } while (0)

#define BAR() __builtin_amdgcn_s_barrier()
#define VM4() asm volatile("s_waitcnt vmcnt(4)" ::: "memory")
#define VM2() asm volatile("s_waitcnt vmcnt(2)" ::: "memory")
#define VM0() asm volatile("s_waitcnt vmcnt(0)" ::: "memory")

__global__ __launch_bounds__(512, 2) void gemm8_yv(
    const unsigned short* __restrict__ A, const unsigned short* __restrict__ Bt,
    unsigned short* __restrict__ y, unsigned short* __restrict__ vt)
{
  const int row0 = blockIdx.y * 256;
  const int col0 = blockIdx.x * 256;
  const unsigned short* Az = A;
  const unsigned short* Bz = Bt;
  const int lda = 1024, ldb = 1024;

  __shared__ __align__(16) char lds[131072];

  const int tid = threadIdx.x;
  const int wave = tid >> 6, lane = tid & 63;
  const int wr = wave >> 2, wc = wave & 3;
  const int srow = lane >> 3, sgrp = (lane & 7) ^ srow;
  const int kbyte = (lane >> 4) * 16;
  const int nt = 8;

  f32x4 acc[8][4];
  #pragma unroll
  for (int m = 0; m < 8; ++m)
    #pragma unroll
    for (int n = 0; n < 4; ++n) acc[m][n] = (f32x4)0.0f;
  short8 a[4][2], b0[2][2], b1[2][2];

  STG(0, 1, 0, 0); STG(0, 1, 1, 0); STG(0, 0, 0, 0); STG(0, 0, 1, 0);
  STG(1, 1, 0, 1); STG(1, 1, 1, 1);
  VM4(); BAR();

  for (int t = 0; t < nt; ++t) {
    const bool pf = (t < nt - 1);
    LDA8(a, 0, 0); LDB4(b0, 0, 0);
    STG(1, 0, 0, 2 * t + 1);
    BAR(); MFMA16(0, 0, a, b0); BAR();
    LDB4(b1, 0, 1);
    STG(1, 0, 1, 2 * t + 1);
    BAR(); MFMA16(0, 1, a, b1); BAR();
    LDA8(a, 0, 1);
    if (pf) STG(0, 1, 0, 2 * t + 2);
    BAR(); MFMA16(1, 1, a, b1); BAR();
    if (pf) STG(0, 1, 1, 2 * t + 2);
    BAR(); MFMA16(1, 0, a, b0);
    if (pf) VM4(); else VM0();
    BAR();
    LDA8(a, 1, 0); LDB4(b0, 1, 0);
    if (pf) STG(0, 0, 0, 2 * t + 2);
    BAR(); MFMA16(0, 0, a, b0); BAR();
    LDB4(b1, 1, 1);
    if (pf) STG(0, 0, 1, 2 * t + 2);
    BAR(); MFMA16(0, 1, a, b1); BAR();
    LDA8(a, 1, 1);
    if (pf) STG(1, 1, 0, 2 * t + 3);
    BAR(); MFMA16(1, 1, a, b1); BAR();
    if (pf) STG(1, 1, 1, 2 * t + 3);
    BAR(); MFMA16(1, 0, a, b0);
    if (pf) VM4();
    BAR();
  }

  const int orow = row0 + wr * 128 + ((lane >> 4) << 2);
  const int ocol = col0 + wc * 64 + (lane & 15);
  if (col0 < 1024) {
    #pragma unroll
    for (int m = 0; m < 8; ++m)
      #pragma unroll
      for (int r = 0; r < 4; ++r) {
        const int rg = orow + m * 16 + r;
        #pragma unroll
        for (int n = 0; n < 4; ++n)
          y[(long long)rg * 1024 + ocol + n * 16] = f2b(acc[m][n][r]);
      }
  } else {
    const int b = row0 >> 11;
    const int t0 = (row0 & 2047) + wr * 128 + ((lane >> 4) << 2);
    const int d0 = (col0 - 1024) + wc * 64 + (lane & 15);
    #pragma unroll
    for (int n = 0; n < 4; ++n) {
      unsigned short* vrow = vt + ((long long)b * 1024 + d0 + n * 16) * 2048 + t0;
      #pragma unroll
      for (int m = 0; m < 8; ++m) {
        short4v v;
        v[0] = (short)f2b(acc[m][n][0]);
        v[1] = (short)f2b(acc[m][n][1]);
        v[2] = (short)f2b(acc[m][n][2]);
        v[3] = (short)f2b(acc[m][n][3]);
        *(short4v*)(vrow + m * 16) = v;
      }
    }
  }
}

// ==================== 256x128 8-phase GEMM (P and PV) ====================
// A 256xK, B 128xK. LDS: A 2x32KB at 0, B 2x16KB at 65536. 96KB total.
// 8 waves: wr in {0,1} (128 rows), wc in {0..3} (32 cols), 2 n-frags/wave.
#define STGA2(buf, half, kt) do {                                              \
    _Pragma("unroll")                                                          \
    for (int _i = 0; _i < 2; ++_i) {                                           \
      const int _c = wave * 2 + _i;                                            \
      gload16(Az + (long long)(row0 + (half) * 128 + _c * 8 + srow) * lda +    \
                  (kt) * 64 + sgrp * 8,                                        \
              lds + (buf) * 32768 + (half) * 16384 + _c * 1024);               \
    } } while (0)

#define STGB2(buf, half, kt)                                                   \
    gload16(Bz + (long long)(col0 + (half) * 64 + wave * 8 + srow) * ldb +     \
                (kt) * 64 + sgrp * 8,                                          \
            lds + 65536 + (buf) * 16384 + (half) * 8192 + wave * 1024)

#define LDA8N(dst, buf, mh) do {                                               \
    _Pragma("unroll")                                                          \
    for (int _m = 0; _m < 4; ++_m) {                                           \
      const int _r = wr * 128 + ((mh) * 4 + _m) * 16 + (lane & 15);            \
      const char* _p = lds + (buf) * 32768 + _r * 128;                         \
      const int _x = (_r & 7) << 4;                                            \
      dst[_m][0] = *(const short8*)(_p + ((kbyte) ^ _x));                      \
      dst[_m][1] = *(const short8*)(_p + ((64 + kbyte) ^ _x));                 \
    } } while (0)

#define LDB1N(dst, buf, nf) do {                                               \
    const int _r = wc * 32 + (nf) * 16 + (lane & 15);                          \
    const char* _p = lds + 65536 + (buf) * 16384 + _r * 128;                   \
    const int _x = (_r & 7) << 4;                                              \
    dst[0] = *(const short8*)(_p + ((kbyte) ^ _x));                            \
    dst[1] = *(const short8*)(_p + ((64 + kbyte) ^ _x));                       \
  } while (0)

#define MFMA8N(mh, nf, av, bv) do {                                            \
    __builtin_amdgcn_s_setprio(1);                                             \
    _Pragma("unroll") for (int _m = 0; _m < 4; ++_m)                           \
    _Pragma("unroll") for (int _k = 0; _k < 2; ++_k)                           \
      acc[(mh)*4+_m][nf] = __builtin_amdgcn_mfma_f32_16x16x32_bf16(            \
          av[_m][_k], bv[_k], acc[(mh)*4+_m][nf], 0, 0, 0);                    \
    __builtin_amdgcn_s_setprio(0);                                             \
  } while (0)

// MODE 1: P = exp(s/32) causal bf16 + rowsum atomics (A=y, B=xb, K=1024)
// MODE 2: PV fp32 out / atomic, scaled by 1/sums (A=P, B=Vt, K chunked)
template<int MODE>
__global__ __launch_bounds__(512, 2) void gemm8n(
    const unsigned short* __restrict__ Abase, const unsigned short* __restrict__ Bbase,
    void* __restrict__ outv, float* __restrict__ sums)
{
  const int z = blockIdx.z;
  const int f = blockIdx.x;
  int row0, col0, k0, nt;
  bool atomic = false;
  const unsigned short *Az, *Bz;
  int lda, ldb;

  if (MODE == 1) {
    int by = (int)((sqrtf(4.f * f + 1.f) - 1.f) * 0.5f);
    while (by * (by + 1) > f) --by;
    while ((by + 1) * (by + 2) <= f) ++by;
    const int bx = f - by * (by + 1);
    row0 = by * 256; col0 = bx * 128; k0 = 0; nt = 8;
    Az = Abase + (long long)z * (2048 * 1024);
    Bz = Bbase + (long long)z * (2048 * 1024);
    lda = 1024; ldb = 1024;
  } else {
    int by, bx;
    if (f < 64) {           // split stripes (by 7..4), chunks of <=1024
      by = 7 - (f >> 4);
      const int c = (f >> 3) & 1;
      bx = f & 7;
      k0 = c * 1024;
      const int kEnd = 256 * (by + 1);
      nt = ((c == 0 ? 1024 : kEnd - 1024) >> 7);
      atomic = true;
    } else {                // single-chunk stripes (by 3..0)
      const int g = f - 64;
      by = 3 - (g >> 3);
      bx = g & 7;
      k0 = 0;
      nt = (256 * (by + 1)) >> 7;
    }
    row0 = by * 256; col0 = bx * 128;
    Az = Abase + (long long)z * (2048 * 2048) + k0;
    Bz = Bbase + (long long)z * (1024 * 2048) + k0;
    lda = 2048; ldb = 2048;
  }

  __shared__ __align__(16) char lds[98304];

  const int tid = threadIdx.x;
  const int wave = tid >> 6, lane = tid & 63;
  const int wr = wave >> 2, wc = wave & 3;
  const int srow = lane >> 3, sgrp = (lane & 7) ^ srow;
  const int kbyte = (lane >> 4) * 16;

  f32x4 acc[8][2];
  #pragma unroll
  for (int m = 0; m < 8; ++m) { acc[m][0] = (f32x4)0.0f; acc[m][1] = (f32x4)0.0f; }
  short8 a[4][2], b0[2], b1[2];

  // prologue: buf0 full (6 loads) + buf1.B (2 loads)
  STGB2(0, 0, 0); STGB2(0, 1, 0); STGA2(0, 0, 0); STGA2(0, 1, 0);
  STGB2(1, 0, 1); STGB2(1, 1, 1);
  VM2(); BAR();

  for (int t = 0; t < nt; ++t) {
    const bool pf = (t < nt - 1);
    // ph1: stage buf1.A-h0 (tile 2t+1)
    LDA8N(a, 0, 0); LDB1N(b0, 0, 0);
    STGA2(1, 0, 2 * t + 1);
    BAR(); MFMA8N(0, 0, a, b0); BAR();
    // ph2: stage buf1.A-h1      (buf0.B dead after this phase)
    LDB1N(b1, 0, 1);
    STGA2(1, 1, 2 * t + 1);
    BAR(); MFMA8N(0, 1, a, b1); BAR();
    // ph3: stage buf0.B-h0 (tile 2t+2)
    LDA8N(a, 0, 1);
    if (pf) STGB2(0, 0, 2 * t + 2);
    BAR(); MFMA8N(1, 1, a, b1); BAR();
    // ph4: stage buf0.B-h1; wait buf1 ready (leave 2 newest)
    if (pf) STGB2(0, 1, 2 * t + 2);
    BAR(); MFMA8N(1, 0, a, b0);
    if (pf) VM2(); else VM0();
    BAR();
    // ph5: stage buf0.A-h0 (tile 2t+2)
    LDA8N(a, 1, 0); LDB1N(b0, 1, 0);
    if (pf) STGA2(0, 0, 2 * t + 2);
    BAR(); MFMA8N(0, 0, a, b0); BAR();
    // ph6: stage buf0.A-h1
    LDB1N(b1, 1, 1);
    if (pf) STGA2(0, 1, 2 * t + 2);
    BAR(); MFMA8N(0, 1, a, b1); BAR();
    // ph7: stage buf1.B-h0 (tile 2t+3)
    LDA8N(a, 1, 1);
    if (pf) STGB2(1, 0, 2 * t + 3);
    BAR(); MFMA8N(1, 1, a, b1); BAR();
    // ph8: stage buf1.B-h1; wait buf0 ready
    if (pf) STGB2(1, 1, 2 * t + 3);
    BAR(); MFMA8N(1, 0, a, b0);
    if (pf) VM2();
    BAR();
  }

  const int orow = row0 + wr * 128 + ((lane >> 4) << 2);
  const int ocol = col0 + wc * 32 + (lane & 15);
  if (MODE == 1) {
    unsigned short* out = (unsigned short*)outv + (long long)z * (2048 * 2048);
    #pragma unroll
    for (int m = 0; m < 8; ++m)
      #pragma unroll
      for (int r = 0; r < 4; ++r) {
        const int rg = orow + m * 16 + r;
        float rs = 0.f;
        #pragma unroll
        for (int n = 0; n < 2; ++n) {
          const int cg = ocol + n * 16;
          float p = (cg > rg) ? 0.0f : __expf(acc[m][n][r] * 0.03125f);
          rs += p;
          out[(long long)rg * 2048 + cg] = f2b(p);
        }
        #pragma unroll
        for (int off = 1; off < 16; off <<= 1) rs += __shfl_xor(rs, off);
        if ((lane & 15) == 0) atomicAdd(&sums[(long long)z * 2048 + rg], rs);
      }
  } else {
    float* oz = (float*)outv + (long long)z * (2048 * 1024);
    const float* sz = sums + (long long)z * 2048;
    #pragma unroll
    for (int m = 0; m < 8; ++m)
      #pragma unroll
      for (int r = 0; r < 4; ++r) {
        const int rg = orow + m * 16 + r;
        const float iv = 1.0f / sz[rg];
        #pragma unroll
        for (int n = 0; n < 2; ++n) {
          float* p = oz + (long long)rg * 1024 + ocol + n * 16;
          const float val = acc[m][n][r] * iv;
          if (atomic) atomicAdd(p, val);
          else *p = val;
        }
      }
  }
}

extern "C" void kernel_launch(void* const* d_in, const int* in_sizes, int n_in,
                              void* d_out, int out_size, void* d_ws, size_t ws_size,
                              hipStream_t stream) {
  (void)in_sizes; (void)n_in; (void)out_size; (void)ws_size;
  const float* x  = (const float*)d_in[0];
  const float* Wq = (const float*)d_in[1];
  const float* Wk = (const float*)d_in[2];
  const float* Wv = (const float*)d_in[3];
  float* out = (float*)d_out;

  char* ws = (char*)d_ws;
  unsigned short* xb  = (unsigned short*)(ws);               // 8192x1024 bf16
  unsigned short* Wt2 = (unsigned short*)(ws + 16777216);    // [2048][1024]: M^T ; Wv^T
  unsigned short* y   = (unsigned short*)(ws + 20971520);    // 8192x1024 bf16
  unsigned short* Vt  = (unsigned short*)(ws + 37748736);    // 4x1024x2048 bf16
  unsigned short* P   = (unsigned short*)(ws + 54525952);    // 4x2048x2048 bf16
  float*          sums = (float*)(ws + 88080384);            // 4x2048 fp32

  // 1. prep: cvt x, transpose Wv, M^T = Wk.Wq^T, zero sums, zero out rows>=1024
  prep<<<13600, 256, 0, stream>>>(x, Wq, Wk, Wv, xb, Wt2, sums, out);

  // 2. [y | V] = x . [M^T ; Wv^T]^T  (256 gemm8 blocks)
  gemm8_yv<<<dim3(8, 32), 512, 0, stream>>>(xb, Wt2, y, Vt);

  // 3. P = exp((y x^T)/32) causal + rowsums  (256x128 8-phase, 288 blocks)
  gemm8n<1><<<dim3(72, 1, 4), 512, 0, stream>>>(y, xb, P, sums);

  // 4. context = (P Vt^T)/rowsum  (256x128 8-phase, K-split, 384 blocks)
  gemm8n<2><<<dim3(96, 1, 4), 512, 0, stream>>>(P, Vt, out, sums);
}

// Round 10
// 162.634 us; speedup vs baseline: 1.1812x; 1.1812x over previous
//
#include <hip/hip_runtime.h>
#include <hip/hip_bf16.h>
#include <stdint.h>

typedef short short8 __attribute__((ext_vector_type(8)));
typedef short short4v __attribute__((ext_vector_type(4)));
typedef float f32x4 __attribute__((ext_vector_type(4)));

__device__ __forceinline__ void gload16(const void* g, void* l) {
  __builtin_amdgcn_global_load_lds((const __attribute__((address_space(1))) void*)g,
                                   (__attribute__((address_space(3))) void*)l, 16, 0, 0);
}

__device__ __forceinline__ unsigned short f2b(float f) {
  unsigned int x = __float_as_uint(f);
  x += 0x7fffu + ((x >> 16) & 1u);
  return (unsigned short)(x >> 16);
}

// ==================== prep ====================
// [0,8192) cvt x->xb | [8192,9216) Wv->Wt2_V^T | [9216,9472) M^T=Wk.Wq^T |
// [9472,9504) sums=0 | [9504,13600) zero out rows>=1024 (atomic PV stripes)
__global__ __launch_bounds__(256) void prep(
    const float* __restrict__ x, const float* __restrict__ Wq,
    const float* __restrict__ Wk, const float* __restrict__ Wv,
    unsigned short* __restrict__ xb, unsigned short* __restrict__ Wt2,
    float* __restrict__ sums, float* __restrict__ out)
{
  __shared__ __align__(16) char smem[16384];
  const int bid = blockIdx.x;
  const int tid = threadIdx.x;
  if (bid < 8192) {
    const int i = bid * 256 + tid;
    const float4 f = ((const float4*)x)[i];
    union { unsigned short u[4]; uint2 v; } o;
    o.u[0] = f2b(f.x); o.u[1] = f2b(f.y); o.u[2] = f2b(f.z); o.u[3] = f2b(f.w);
    ((uint2*)xb)[i] = o.v;
  } else if (bid < 9216) {
    float (*tb)[33] = (float(*)[33])smem;
    const int t = bid - 8192;
    const int bx = t & 31, by = t >> 5;
    const int tx = tid & 31, ty = tid >> 5;
    const int xcol = bx * 32 + tx, y0 = by * 32;
    #pragma unroll
    for (int i = 0; i < 4; ++i)
      tb[ty + i * 8][tx] = Wv[(long long)(y0 + ty + i * 8) * 1024 + xcol];
    __syncthreads();
    unsigned short* O = Wt2 + 1024 * 1024;
    const int xo = by * 32 + tx, yo0 = bx * 32;
    #pragma unroll
    for (int i = 0; i < 4; ++i)
      O[(long long)(yo0 + ty + i * 8) * 1024 + xo] = f2b(tb[tx][ty + i * 8]);
  } else if (bid < 9472) {
    const int t = bid - 9216;
    const int bx = t & 15, by = t >> 4;
    const int row0 = by * 64, col0 = bx * 64;
    const int wave = tid >> 6, lane = tid & 63;
    const int wr = wave >> 1, wc = wave & 1;
    const int l15 = lane & 15, lk = lane >> 4;
    const int sr = lane >> 3, sg = lane & 7;
    char* lA = smem;
    char* lB = smem + 8192;
    const int rA = wr * 32 + l15, cB = wc * 32 + l15;
    const int xorA = (rA & 7) << 4, xorB = (cB & 7) << 4;
    const int kb = lk * 16;
    f32x4 acc[2][2];
    #pragma unroll
    for (int m = 0; m < 2; ++m)
      #pragma unroll
      for (int n = 0; n < 2; ++n) acc[m][n] = (f32x4)0.0f;
    for (int kt = 0; kt < 16; ++kt) {
      const int kc = kt * 64;
      short8 va[2], vb[2];
      int rr[2];
      #pragma unroll
      for (int j = 0; j < 2; ++j) {
        const int ci = wave * 2 + j;
        const int r = ci * 8 + sr;
        rr[j] = r;
        const float* pa = Wk + (long long)(row0 + r) * 1024 + kc + sg * 8;
        const float* pb = Wq + (long long)(col0 + r) * 1024 + kc + sg * 8;
        const float4 a0 = *(const float4*)pa, a1 = *(const float4*)(pa + 4);
        const float4 b0 = *(const float4*)pb, b1 = *(const float4*)(pb + 4);
        va[j][0] = (short)f2b(a0.x); va[j][1] = (short)f2b(a0.y);
        va[j][2] = (short)f2b(a0.z); va[j][3] = (short)f2b(a0.w);
        va[j][4] = (short)f2b(a1.x); va[j][5] = (short)f2b(a1.y);
        va[j][6] = (short)f2b(a1.z); va[j][7] = (short)f2b(a1.w);
        vb[j][0] = (short)f2b(b0.x); vb[j][1] = (short)f2b(b0.y);
        vb[j][2] = (short)f2b(b0.z); vb[j][3] = (short)f2b(b0.w);
        vb[j][4] = (short)f2b(b1.x); vb[j][5] = (short)f2b(b1.y);
        vb[j][6] = (short)f2b(b1.z); vb[j][7] = (short)f2b(b1.w);
      }
      __syncthreads();
      #pragma unroll
      for (int j = 0; j < 2; ++j) {
        const int off = rr[j] * 128 + ((sg * 16) ^ ((rr[j] & 7) << 4));
        *(short8*)(lA + off) = va[j];
        *(short8*)(lB + off) = vb[j];
      }
      __syncthreads();
      #pragma unroll
      for (int ks = 0; ks < 2; ++ks) {
        short8 af[2], bf[2];
        #pragma unroll
        for (int m = 0; m < 2; ++m)
          af[m] = *(const short8*)(lA + (rA + m * 16) * 128 + ((ks * 64 + kb) ^ xorA));
        #pragma unroll
        for (int n = 0; n < 2; ++n)
          bf[n] = *(const short8*)(lB + (cB + n * 16) * 128 + ((ks * 64 + kb) ^ xorB));
        #pragma unroll
        for (int m = 0; m < 2; ++m)
          #pragma unroll
          for (int n = 0; n < 2; ++n)
            acc[m][n] = __builtin_amdgcn_mfma_f32_16x16x32_bf16(af[m], bf[n], acc[m][n], 0, 0, 0);
      }
    }
    const int orow = row0 + wr * 32 + lk * 4;
    const int ocol = col0 + wc * 32 + l15;
    #pragma unroll
    for (int m = 0; m < 2; ++m)
      #pragma unroll
      for (int r = 0; r < 4; ++r)
        #pragma unroll
        for (int n = 0; n < 2; ++n)
          Wt2[(long long)(orow + m * 16 + r) * 1024 + ocol + n * 16] = f2b(acc[m][n][r]);
  } else if (bid < 9504) {
    const int i = (bid - 9472) * 256 + tid;
    sums[i] = 0.f;
  } else {
    // zero out[z][1024..2047][*] (16.8 MB), float4 per thread
    const long long i = (long long)(bid - 9504) * 256 + tid;
    const int z = (int)(i >> 18);
    const int r = (int)(i & 262143);
    float4* p = (float4*)(out + (long long)z * 2097152 + 1048576) + r;
    *p = make_float4(0.f, 0.f, 0.f, 0.f);
  }
}

// ==================== 256x256 8-phase GEMM machinery ====================
#define STG(buf, isB, half, kt) do {                                           \
    const unsigned short* _s = (isB) ? Bz : Az;                                \
    const int _ld = (isB) ? ldb : lda;                                         \
    const int _b0 = (isB) ? col0 : row0;                                       \
    char* _d = lds + (buf) * 65536 + (isB) * 32768 + (half) * 16384;           \
    _Pragma("unroll")                                                          \
    for (int _i = 0; _i < 2; ++_i) {                                           \
      const int _c = wave * 2 + _i;                                            \
      const int _row = (half) * 128 + _c * 8 + srow;                           \
      gload16(_s + (long long)(_b0 + _row) * _ld + (kt) * 64 + sgrp * 8,       \
              _d + _c * 1024);                                                 \
    } } while (0)

#define LDA8(dst, buf, mh) do {                                                \
    _Pragma("unroll")                                                          \
    for (int _m = 0; _m < 4; ++_m) {                                           \
      const int _r = wr * 128 + ((mh) * 4 + _m) * 16 + (lane & 15);            \
      const char* _p = lds + (buf) * 65536 + _r * 128;                         \
      const int _x = (_r & 7) << 4;                                            \
      dst[_m][0] = *(const short8*)(_p + ((kbyte) ^ _x));                      \
      dst[_m][1] = *(const short8*)(_p + ((64 + kbyte) ^ _x));                 \
    } } while (0)

#define LDB4(dst, buf, nh) do {                                                \
    _Pragma("unroll")                                                          \
    for (int _n = 0; _n < 2; ++_n) {                                           \
      const int _r = wc * 64 + ((nh) * 2 + _n) * 16 + (lane & 15);             \
      const char* _p = lds + (buf) * 65536 + 32768 + _r * 128;                 \
      const int _x = (_r & 7) << 4;                                            \
      dst[_n][0] = *(const short8*)(_p + ((kbyte) ^ _x));                      \
      dst[_n][1] = *(const short8*)(_p + ((64 + kbyte) ^ _x));                 \
    } } while (0)

#define MFMA16(mh, nh, av, bv) do {                                            \
    __builtin_amdgcn_s_setprio(1);                                             \
    _Pragma("unroll") for (int _n = 0; _n < 2; ++_n)                           \
    _Pragma("unroll") for (int _m = 0; _m < 4; ++_m)                           \
    _Pragma("unroll") for (int _k = 0; _k < 2; ++_k)                           \
      acc[(mh)*4+_m][(nh)*2+_n] = __builtin_amdgcn_mfma_f32_16x16x32_bf16(     \
          av[_m][_k], bv[_n][_k], acc[(mh)*4+_m][(nh)*2+_n], 0, 0, 0);         \
    __builtin_amdgcn_s_setprio(0);                                             \
  } while (0)

#define BAR() __builtin_amdgcn_s_barrier()
#define VM4() asm volatile("s_waitcnt vmcnt(4)" ::: "memory")
#define VM0() asm volatile("s_waitcnt vmcnt(0)" ::: "memory")

#define GEMM8_BODY(NT)                                                         \
  f32x4 acc[8][4];                                                             \
  _Pragma("unroll")                                                            \
  for (int m = 0; m < 8; ++m)                                                  \
    _Pragma("unroll")                                                          \
    for (int n = 0; n < 4; ++n) acc[m][n] = (f32x4)0.0f;                       \
  short8 a[4][2], b0[2][2], b1[2][2];                                          \
  STG(0, 1, 0, 0); STG(0, 1, 1, 0); STG(0, 0, 0, 0); STG(0, 0, 1, 0);          \
  STG(1, 1, 0, 1); STG(1, 1, 1, 1);                                            \
  VM4(); BAR();                                                                \
  for (int t = 0; t < (NT); ++t) {                                             \
    const bool pf = (t < (NT) - 1);                                            \
    LDA8(a, 0, 0); LDB4(b0, 0, 0);                                             \
    STG(1, 0, 0, 2 * t + 1);                                                   \
    BAR(); MFMA16(0, 0, a, b0); BAR();                                         \
    LDB4(b1, 0, 1);                                                            \
    STG(1, 0, 1, 2 * t + 1);                                                   \
    BAR(); MFMA16(0, 1, a, b1); BAR();                                         \
    LDA8(a, 0, 1);                                                             \
    if (pf) STG(0, 1, 0, 2 * t + 2);                                           \
    BAR(); MFMA16(1, 1, a, b1); BAR();                                         \
    if (pf) STG(0, 1, 1, 2 * t + 2);                                           \
    BAR(); MFMA16(1, 0, a, b0);                                                \
    if (pf) VM4(); else VM0();                                                 \
    BAR();                                                                     \
    LDA8(a, 1, 0); LDB4(b0, 1, 0);                                             \
    if (pf) STG(0, 0, 0, 2 * t + 2);                                           \
    BAR(); MFMA16(0, 0, a, b0); BAR();                                         \
    LDB4(b1, 1, 1);                                                            \
    if (pf) STG(0, 0, 1, 2 * t + 2);                                           \
    BAR(); MFMA16(0, 1, a, b1); BAR();                                         \
    LDA8(a, 1, 1);                                                             \
    if (pf) STG(1, 1, 0, 2 * t + 3);                                           \
    BAR(); MFMA16(1, 1, a, b1); BAR();                                         \
    if (pf) STG(1, 1, 1, 2 * t + 3);                                           \
    BAR(); MFMA16(1, 0, a, b0);                                                \
    if (pf) VM4();                                                             \
    BAR();                                                                     \
  }

// ---- [y|V] = x . [M^T ; Wv^T]^T, 256 blocks; y bf16 + Vt transposed out ----
__global__ __launch_bounds__(512, 2) void gemm8_yv(
    const unsigned short* __restrict__ A, const unsigned short* __restrict__ Bt,
    unsigned short* __restrict__ y, unsigned short* __restrict__ vt)
{
  const int row0 = blockIdx.y * 256;
  const int col0 = blockIdx.x * 256;
  const unsigned short* Az = A;
  const unsigned short* Bz = Bt;
  const int lda = 1024, ldb = 1024;

  __shared__ __align__(16) char lds[131072];

  const int tid = threadIdx.x;
  const int wave = tid >> 6, lane = tid & 63;
  const int wr = wave >> 2, wc = wave & 3;
  const int srow = lane >> 3, sgrp = (lane & 7) ^ srow;
  const int kbyte = (lane >> 4) * 16;

  GEMM8_BODY(8)

  const int orow = row0 + wr * 128 + ((lane >> 4) << 2);
  const int ocol = col0 + wc * 64 + (lane & 15);
  if (col0 < 1024) {
    #pragma unroll
    for (int m = 0; m < 8; ++m)
      #pragma unroll
      for (int r = 0; r < 4; ++r) {
        const int rg = orow + m * 16 + r;
        #pragma unroll
        for (int n = 0; n < 4; ++n)
          y[(long long)rg * 1024 + ocol + n * 16] = f2b(acc[m][n][r]);
      }
  } else {
    const int b = row0 >> 11;
    const int t0 = (row0 & 2047) + wr * 128 + ((lane >> 4) << 2);
    const int d0 = (col0 - 1024) + wc * 64 + (lane & 15);
    #pragma unroll
    for (int n = 0; n < 4; ++n) {
      unsigned short* vrow = vt + ((long long)b * 1024 + d0 + n * 16) * 2048 + t0;
      #pragma unroll
      for (int m = 0; m < 8; ++m) {
        short4v v;
        v[0] = (short)f2b(acc[m][n][0]);
        v[1] = (short)f2b(acc[m][n][1]);
        v[2] = (short)f2b(acc[m][n][2]);
        v[3] = (short)f2b(acc[m][n][3]);
        *(short4v*)(vrow + m * 16) = v;
      }
    }
  }
}

// ---- P = exp((y x^T)/32) causal + rowsum atomics ----
__global__ __launch_bounds__(512, 2) void gemm8_p(
    const unsigned short* __restrict__ A, const unsigned short* __restrict__ Bt,
    unsigned short* __restrict__ outp, float* __restrict__ sums)
{
  const int z = blockIdx.z;
  const int row0 = blockIdx.y * 256;
  const int col0 = blockIdx.x * 256;
  if (col0 > row0 + 255) return;

  const unsigned short* Az = A + (long long)z * (2048 * 1024);
  const unsigned short* Bz = Bt + (long long)z * (2048 * 1024);
  const int lda = 1024, ldb = 1024;

  __shared__ __align__(16) char lds[131072];

  const int tid = threadIdx.x;
  const int wave = tid >> 6, lane = tid & 63;
  const int wr = wave >> 2, wc = wave & 3;
  const int srow = lane >> 3, sgrp = (lane & 7) ^ srow;
  const int kbyte = (lane >> 4) * 16;

  GEMM8_BODY(8)

  const int orow = row0 + wr * 128 + ((lane >> 4) << 2);
  const int ocol = col0 + wc * 64 + (lane & 15);
  unsigned short* out = outp + (long long)z * (2048 * 2048);
  #pragma unroll
  for (int m = 0; m < 8; ++m)
    #pragma unroll
    for (int r = 0; r < 4; ++r) {
      const int rg = orow + m * 16 + r;
      float rs = 0.f;
      #pragma unroll
      for (int n = 0; n < 4; ++n) {
        const int cg = ocol + n * 16;
        float p = (cg > rg) ? 0.0f : __expf(acc[m][n][r] * 0.03125f);
        rs += p;
        out[(long long)rg * 2048 + cg] = f2b(p);
      }
      #pragma unroll
      for (int off = 1; off < 16; off <<= 1) rs += __shfl_xor(rs, off);
      if ((lane & 15) == 0) atomicAdd(&sums[(long long)z * 2048 + rg], rs);
    }
}

// ==================== 128x128 2-phase PV (causal K-bound, K-split@1024) ====================
// blockIdx.y in [0,32): q=y>>1 -> stripe by=15-q (longest first), c=y&1 chunk.
// Stripes by>=8 (rows>=1024) have 2 chunks, accumulate via fp32 atomicAdd
// (out rows>=1024 zeroed in prep); by<8 single chunk, direct store.
__global__ __launch_bounds__(256) void gemm_pv(
    const unsigned short* __restrict__ P, const unsigned short* __restrict__ Vt,
    float* __restrict__ out, const float* __restrict__ sums)
{
  const int z = blockIdx.z;
  const int q = blockIdx.y >> 1;
  const int by = 15 - q;
  const int c = blockIdx.y & 1;
  const int nch = (by >= 8) ? 2 : 1;
  if (c >= nch) return;
  const int row0 = by * 128;
  const int col0 = blockIdx.x * 128;
  const int k0 = c * 1024;
  const int kEnd = min(row0 + 128, k0 + 1024);
  const int nkt = (kEnd - k0) >> 6;
  const bool atom = (nch > 1);

  const unsigned short* Az = P + (long long)z * (2048 * 2048) + k0;
  const unsigned short* Bz = Vt + (long long)z * (1024 * 2048) + k0;

  __shared__ __align__(16) char lds[32768];

  const int tid = threadIdx.x;
  const int wave = tid >> 6;
  const int lane = tid & 63;
  const int wr = wave >> 1, wc = wave & 1;
  const int l15 = lane & 15, lk = lane >> 4;

  const int srow = lane >> 3;
  const int sgrp = (lane & 7) ^ srow;

  const int rA = wr * 64 + l15;
  const int cB = wc * 64 + l15;
  const int kb = lk * 16;
  const int xorA = (rA & 7) << 4;
  const int xorB = (cB & 7) << 4;

  f32x4 acc[4][4];
  #pragma unroll
  for (int m = 0; m < 4; ++m)
    #pragma unroll
    for (int n = 0; n < 4; ++n) acc[m][n] = (f32x4)0.0f;

  for (int kt = 0; kt < nkt; ++kt) {
    const int kc = kt * 64;
    #pragma unroll
    for (int i = 0; i < 4; ++i) {
      const int ci = wave * 4 + i;
      gload16(Az + (long long)(row0 + ci * 8 + srow) * 2048 + kc + sgrp * 8,
              lds + ci * 1024);
      gload16(Bz + (long long)(col0 + ci * 8 + srow) * 2048 + kc + sgrp * 8,
              lds + 16384 + ci * 1024);
    }
    __syncthreads();
    #pragma unroll
    for (int ks = 0; ks < 2; ++ks) {
      short8 af[4], bfr[4];
      #pragma unroll
      for (int m = 0; m < 4; ++m)
        af[m] = *(const short8*)(lds + (rA + m * 16) * 128 + ((ks * 64 + kb) ^ xorA));
      #pragma unroll
      for (int n = 0; n < 4; ++n)
        bfr[n] = *(const short8*)(lds + 16384 + (cB + n * 16) * 128 + ((ks * 64 + kb) ^ xorB));
      #pragma unroll
      for (int m = 0; m < 4; ++m)
        #pragma unroll
        for (int n = 0; n < 4; ++n)
          acc[m][n] = __builtin_amdgcn_mfma_f32_16x16x32_bf16(af[m], bfr[n], acc[m][n], 0, 0, 0);
    }
    __syncthreads();
  }

  const int orow = row0 + wr * 64 + lk * 4;
  const int ocol = col0 + wc * 64 + l15;
  const float* sz = sums + (long long)z * 2048;
  float* oz = out + (long long)z * (2048 * 1024);
  #pragma unroll
  for (int m = 0; m < 4; ++m)
    #pragma unroll
    for (int r = 0; r < 4; ++r) {
      const int rg = orow + m * 16 + r;
      const float iv = 1.0f / sz[rg];
      #pragma unroll
      for (int n = 0; n < 4; ++n) {
        float* p = oz + (long long)rg * 1024 + ocol + n * 16;
        const float val = acc[m][n][r] * iv;
        if (atom) atomicAdd(p, val);
        else *p = val;
      }
    }
}

extern "C" void kernel_launch(void* const* d_in, const int* in_sizes, int n_in,
                              void* d_out, int out_size, void* d_ws, size_t ws_size,
                              hipStream_t stream) {
  (void)in_sizes; (void)n_in; (void)out_size; (void)ws_size;
  const float* x  = (const float*)d_in[0];
  const float* Wq = (const float*)d_in[1];
  const float* Wk = (const float*)d_in[2];
  const float* Wv = (const float*)d_in[3];
  float* out = (float*)d_out;

  char* ws = (char*)d_ws;
  unsigned short* xb  = (unsigned short*)(ws);               // 8192x1024 bf16
  unsigned short* Wt2 = (unsigned short*)(ws + 16777216);    // [2048][1024]: M^T ; Wv^T
  unsigned short* y   = (unsigned short*)(ws + 20971520);    // 8192x1024 bf16
  unsigned short* Vt  = (unsigned short*)(ws + 37748736);    // 4x1024x2048 bf16
  unsigned short* P   = (unsigned short*)(ws + 54525952);    // 4x2048x2048 bf16
  float*          sums = (float*)(ws + 88080384);            // 4x2048 fp32

  // 1. prep: cvt x, transpose Wv, M^T = Wk.Wq^T, zero sums, zero out rows>=1024
  prep<<<13600, 256, 0, stream>>>(x, Wq, Wk, Wv, xb, Wt2, sums, out);

  // 2. [y | V] = x . [M^T ; Wv^T]^T  (256 gemm8 blocks)
  gemm8_yv<<<dim3(8, 32), 512, 0, stream>>>(xb, Wt2, y, Vt);

  // 3. P = exp((y x^T)/32) causal, unnormalized bf16 + rowsums
  gemm8_p<<<dim3(8, 8, 4), 512, 0, stream>>>(y, xb, P, sums);

  // 4. context = (P Vt^T)/rowsum  (128^2 2-phase, K-split@1024, 768 active blocks)
  gemm_pv<<<dim3(8, 32, 4), 256, 0, stream>>>(P, Vt, out, sums);
}

// Round 11
// 153.258 us; speedup vs baseline: 1.2535x; 1.0612x over previous
//
#include <hip/hip_runtime.h>
#include <hip/hip_bf16.h>
#include <stdint.h>

typedef short short8 __attribute__((ext_vector_type(8)));
typedef short short4v __attribute__((ext_vector_type(4)));
typedef float f32x4 __attribute__((ext_vector_type(4)));

__device__ __forceinline__ void gload16(const void* g, void* l) {
  __builtin_amdgcn_global_load_lds((const __attribute__((address_space(1))) void*)g,
                                   (__attribute__((address_space(3))) void*)l, 16, 0, 0);
}

__device__ __forceinline__ unsigned short f2b(float f) {
  unsigned int x = __float_as_uint(f);
  x += 0x7fffu + ((x >> 16) & 1u);
  return (unsigned short)(x >> 16);
}

// ==================== prep ====================
// [0,8192) cvt x->xb | [8192,9216) Wv->Wt2_V^T | [9216,9472) M^T=Wk.Wq^T | [9472,9504) sums=0
__global__ __launch_bounds__(256) void prep(
    const float* __restrict__ x, const float* __restrict__ Wq,
    const float* __restrict__ Wk, const float* __restrict__ Wv,
    unsigned short* __restrict__ xb, unsigned short* __restrict__ Wt2,
    float* __restrict__ sums)
{
  __shared__ __align__(16) char smem[16384];
  const int bid = blockIdx.x;
  const int tid = threadIdx.x;
  if (bid < 8192) {
    const int i = bid * 256 + tid;
    const float4 f = ((const float4*)x)[i];
    union { unsigned short u[4]; uint2 v; } o;
    o.u[0] = f2b(f.x); o.u[1] = f2b(f.y); o.u[2] = f2b(f.z); o.u[3] = f2b(f.w);
    ((uint2*)xb)[i] = o.v;
  } else if (bid < 9216) {
    float (*tb)[33] = (float(*)[33])smem;
    const int t = bid - 8192;
    const int bx = t & 31, by = t >> 5;
    const int tx = tid & 31, ty = tid >> 5;
    const int xcol = bx * 32 + tx, y0 = by * 32;
    #pragma unroll
    for (int i = 0; i < 4; ++i)
      tb[ty + i * 8][tx] = Wv[(long long)(y0 + ty + i * 8) * 1024 + xcol];
    __syncthreads();
    unsigned short* O = Wt2 + 1024 * 1024;
    const int xo = by * 32 + tx, yo0 = bx * 32;
    #pragma unroll
    for (int i = 0; i < 4; ++i)
      O[(long long)(yo0 + ty + i * 8) * 1024 + xo] = f2b(tb[tx][ty + i * 8]);
  } else if (bid < 9472) {
    const int t = bid - 9216;
    const int bx = t & 15, by = t >> 4;
    const int row0 = by * 64, col0 = bx * 64;
    const int wave = tid >> 6, lane = tid & 63;
    const int wr = wave >> 1, wc = wave & 1;
    const int l15 = lane & 15, lk = lane >> 4;
    const int sr = lane >> 3, sg = lane & 7;
    char* lA = smem;
    char* lB = smem + 8192;
    const int rA = wr * 32 + l15, cB = wc * 32 + l15;
    const int xorA = (rA & 7) << 4, xorB = (cB & 7) << 4;
    const int kb = lk * 16;
    f32x4 acc[2][2];
    #pragma unroll
    for (int m = 0; m < 2; ++m)
      #pragma unroll
      for (int n = 0; n < 2; ++n) acc[m][n] = (f32x4)0.0f;
    for (int kt = 0; kt < 16; ++kt) {
      const int kc = kt * 64;
      short8 va[2], vb[2];
      int rr[2];
      #pragma unroll
      for (int j = 0; j < 2; ++j) {
        const int ci = wave * 2 + j;
        const int r = ci * 8 + sr;
        rr[j] = r;
        const float* pa = Wk + (long long)(row0 + r) * 1024 + kc + sg * 8;
        const float* pb = Wq + (long long)(col0 + r) * 1024 + kc + sg * 8;
        const float4 a0 = *(const float4*)pa, a1 = *(const float4*)(pa + 4);
        const float4 b0 = *(const float4*)pb, b1 = *(const float4*)(pb + 4);
        va[j][0] = (short)f2b(a0.x); va[j][1] = (short)f2b(a0.y);
        va[j][2] = (short)f2b(a0.z); va[j][3] = (short)f2b(a0.w);
        va[j][4] = (short)f2b(a1.x); va[j][5] = (short)f2b(a1.y);
        va[j][6] = (short)f2b(a1.z); va[j][7] = (short)f2b(a1.w);
        vb[j][0] = (short)f2b(b0.x); vb[j][1] = (short)f2b(b0.y);
        vb[j][2] = (short)f2b(b0.z); vb[j][3] = (short)f2b(b0.w);
        vb[j][4] = (short)f2b(b1.x); vb[j][5] = (short)f2b(b1.y);
        vb[j][6] = (short)f2b(b1.z); vb[j][7] = (short)f2b(b1.w);
      }
      __syncthreads();
      #pragma unroll
      for (int j = 0; j < 2; ++j) {
        const int off = rr[j] * 128 + ((sg * 16) ^ ((rr[j] & 7) << 4));
        *(short8*)(lA + off) = va[j];
        *(short8*)(lB + off) = vb[j];
      }
      __syncthreads();
      #pragma unroll
      for (int ks = 0; ks < 2; ++ks) {
        short8 af[2], bf[2];
        #pragma unroll
        for (int m = 0; m < 2; ++m)
          af[m] = *(const short8*)(lA + (rA + m * 16) * 128 + ((ks * 64 + kb) ^ xorA));
        #pragma unroll
        for (int n = 0; n < 2; ++n)
          bf[n] = *(const short8*)(lB + (cB + n * 16) * 128 + ((ks * 64 + kb) ^ xorB));
        #pragma unroll
        for (int m = 0; m < 2; ++m)
          #pragma unroll
          for (int n = 0; n < 2; ++n)
            acc[m][n] = __builtin_amdgcn_mfma_f32_16x16x32_bf16(af[m], bf[n], acc[m][n], 0, 0, 0);
      }
    }
    const int orow = row0 + wr * 32 + lk * 4;
    const int ocol = col0 + wc * 32 + l15;
    #pragma unroll
    for (int m = 0; m < 2; ++m)
      #pragma unroll
      for (int r = 0; r < 4; ++r)
        #pragma unroll
        for (int n = 0; n < 2; ++n)
          Wt2[(long long)(orow + m * 16 + r) * 1024 + ocol + n * 16] = f2b(acc[m][n][r]);
  } else {
    const int i = (bid - 9472) * 256 + tid;
    sums[i] = 0.f;
  }
}

// ==================== 256x256 8-phase GEMM machinery ====================
#define STG(buf, isB, half, kt) do {                                           \
    const unsigned short* _s = (isB) ? Bz : Az;                                \
    const int _ld = (isB) ? ldb : lda;                                         \
    const int _b0 = (isB) ? col0 : row0;                                       \
    char* _d = lds + (buf) * 65536 + (isB) * 32768 + (half) * 16384;           \
    _Pragma("unroll")                                                          \
    for (int _i = 0; _i < 2; ++_i) {                                           \
      const int _c = wave * 2 + _i;                                            \
      const int _row = (half) * 128 + _c * 8 + srow;                           \
      gload16(_s + (long long)(_b0 + _row) * _ld + (kt) * 64 + sgrp * 8,       \
              _d + _c * 1024);                                                 \
    } } while (0)

#define LDA8(dst, buf, mh) do {                                                \
    _Pragma("unroll")                                                          \
    for (int _m = 0; _m < 4; ++_m) {                                           \
      const int _r = wr * 128 + ((mh) * 4 + _m) * 16 + (lane & 15);            \
      const char* _p = lds + (buf) * 65536 + _r * 128;                         \
      const int _x = (_r & 7) << 4;                                            \
      dst[_m][0] = *(const short8*)(_p + ((kbyte) ^ _x));                      \
      dst[_m][1] = *(const short8*)(_p + ((64 + kbyte) ^ _x));                 \
    } } while (0)

#define LDB4(dst, buf, nh) do {                                                \
    _Pragma("unroll")                                                          \
    for (int _n = 0; _n < 2; ++_n) {                                           \
      const int _r = wc * 64 + ((nh) * 2 + _n) * 16 + (lane & 15);             \
      const char* _p = lds + (buf) * 65536 + 32768 + _r * 128;                 \
      const int _x = (_r & 7) << 4;                                            \
      dst[_n][0] = *(const short8*)(_p + ((kbyte) ^ _x));                      \
      dst[_n][1] = *(const short8*)(_p + ((64 + kbyte) ^ _x));                 \
    } } while (0)

#define MFMA16(mh, nh, av, bv) do {                                            \
    __builtin_amdgcn_s_setprio(1);                                             \
    _Pragma("unroll") for (int _n = 0; _n < 2; ++_n)                           \
    _Pragma("unroll") for (int _m = 0; _m < 4; ++_m)                           \
    _Pragma("unroll") for (int _k = 0; _k < 2; ++_k)                           \
      acc[(mh)*4+_m][(nh)*2+_n] = __builtin_amdgcn_mfma_f32_16x16x32_bf16(     \
          av[_m][_k], bv[_n][_k], acc[(mh)*4+_m][(nh)*2+_n], 0, 0, 0);         \
    __builtin_amdgcn_s_setprio(0);                                             \
  } while (0)

#define BAR() __builtin_amdgcn_s_barrier()
#define VM4() asm volatile("s_waitcnt vmcnt(4)" ::: "memory")
#define VM0() asm volatile("s_waitcnt vmcnt(0)" ::: "memory")

#define GEMM8_BODY(NT)                                                         \
  f32x4 acc[8][4];                                                             \
  _Pragma("unroll")                                                            \
  for (int m = 0; m < 8; ++m)                                                  \
    _Pragma("unroll")                                                          \
    for (int n = 0; n < 4; ++n) acc[m][n] = (f32x4)0.0f;                       \
  short8 a[4][2], b0[2][2], b1[2][2];                                          \
  STG(0, 1, 0, 0); STG(0, 1, 1, 0); STG(0, 0, 0, 0); STG(0, 0, 1, 0);          \
  STG(1, 1, 0, 1); STG(1, 1, 1, 1);                                            \
  VM4(); BAR();                                                                \
  for (int t = 0; t < (NT); ++t) {                                             \
    const bool pf = (t < (NT) - 1);                                            \
    LDA8(a, 0, 0); LDB4(b0, 0, 0);                                             \
    STG(1, 0, 0, 2 * t + 1);                                                   \
    BAR(); MFMA16(0, 0, a, b0); BAR();                                         \
    LDB4(b1, 0, 1);                                                            \
    STG(1, 0, 1, 2 * t + 1);                                                   \
    BAR(); MFMA16(0, 1, a, b1); BAR();                                         \
    LDA8(a, 0, 1);                                                             \
    if (pf) STG(0, 1, 0, 2 * t + 2);                                           \
    BAR(); MFMA16(1, 1, a, b1); BAR();                                         \
    if (pf) STG(0, 1, 1, 2 * t + 2);                                           \
    BAR(); MFMA16(1, 0, a, b0);                                                \
    if (pf) VM4(); else VM0();                                                 \
    BAR();                                                                     \
    LDA8(a, 1, 0); LDB4(b0, 1, 0);                                             \
    if (pf) STG(0, 0, 0, 2 * t + 2);                                           \
    BAR(); MFMA16(0, 0, a, b0); BAR();                                         \
    LDB4(b1, 1, 1);                                                            \
    if (pf) STG(0, 0, 1, 2 * t + 2);                                           \
    BAR(); MFMA16(0, 1, a, b1); BAR();                                         \
    LDA8(a, 1, 1);                                                             \
    if (pf) STG(1, 1, 0, 2 * t + 3);                                           \
    BAR(); MFMA16(1, 1, a, b1); BAR();                                         \
    if (pf) STG(1, 1, 1, 2 * t + 3);                                           \
    BAR(); MFMA16(1, 0, a, b0);                                                \
    if (pf) VM4();                                                             \
    BAR();                                                                     \
  }

// ---- [y|V] = x . [M^T ; Wv^T]^T ; grid (x=row 32, y=col 8) for XCD grouping:
// linear id = r + 32c -> id%8 = r%8, so all 8 col-blocks of a row-panel share one XCD.
__global__ __launch_bounds__(512, 2) void gemm8_yv(
    const unsigned short* __restrict__ A, const unsigned short* __restrict__ Bt,
    unsigned short* __restrict__ y, unsigned short* __restrict__ vt)
{
  const int row0 = blockIdx.x * 256;
  const int col0 = blockIdx.y * 256;
  const unsigned short* Az = A;
  const unsigned short* Bz = Bt;
  const int lda = 1024, ldb = 1024;

  __shared__ __align__(16) char lds[131072];

  const int tid = threadIdx.x;
  const int wave = tid >> 6, lane = tid & 63;
  const int wr = wave >> 2, wc = wave & 3;
  const int srow = lane >> 3, sgrp = (lane & 7) ^ srow;
  const int kbyte = (lane >> 4) * 16;

  GEMM8_BODY(8)

  const int orow = row0 + wr * 128 + ((lane >> 4) << 2);
  const int ocol = col0 + wc * 64 + (lane & 15);
  if (col0 < 1024) {
    #pragma unroll
    for (int m = 0; m < 8; ++m)
      #pragma unroll
      for (int r = 0; r < 4; ++r) {
        const int rg = orow + m * 16 + r;
        #pragma unroll
        for (int n = 0; n < 4; ++n)
          y[(long long)rg * 1024 + ocol + n * 16] = f2b(acc[m][n][r]);
      }
  } else {
    const int b = row0 >> 11;
    const int t0 = (row0 & 2047) + wr * 128 + ((lane >> 4) << 2);
    const int d0 = (col0 - 1024) + wc * 64 + (lane & 15);
    #pragma unroll
    for (int n = 0; n < 4; ++n) {
      unsigned short* vrow = vt + ((long long)b * 1024 + d0 + n * 16) * 2048 + t0;
      #pragma unroll
      for (int m = 0; m < 8; ++m) {
        short4v v;
        v[0] = (short)f2b(acc[m][n][0]);
        v[1] = (short)f2b(acc[m][n][1]);
        v[2] = (short)f2b(acc[m][n][2]);
        v[3] = (short)f2b(acc[m][n][3]);
        *(short4v*)(vrow + m * 16) = v;
      }
    }
  }
}

// ---- P = exp((y x^T)/32) causal + rowsum atomics ----
__global__ __launch_bounds__(512, 2) void gemm8_p(
    const unsigned short* __restrict__ A, const unsigned short* __restrict__ Bt,
    unsigned short* __restrict__ outp, float* __restrict__ sums)
{
  const int z = blockIdx.z;
  const int row0 = blockIdx.y * 256;
  const int col0 = blockIdx.x * 256;
  if (col0 > row0 + 255) return;

  const unsigned short* Az = A + (long long)z * (2048 * 1024);
  const unsigned short* Bz = Bt + (long long)z * (2048 * 1024);
  const int lda = 1024, ldb = 1024;

  __shared__ __align__(16) char lds[131072];

  const int tid = threadIdx.x;
  const int wave = tid >> 6, lane = tid & 63;
  const int wr = wave >> 2, wc = wave & 3;
  const int srow = lane >> 3, sgrp = (lane & 7) ^ srow;
  const int kbyte = (lane >> 4) * 16;

  GEMM8_BODY(8)

  const int orow = row0 + wr * 128 + ((lane >> 4) << 2);
  const int ocol = col0 + wc * 64 + (lane & 15);
  unsigned short* out = outp + (long long)z * (2048 * 2048);
  #pragma unroll
  for (int m = 0; m < 8; ++m)
    #pragma unroll
    for (int r = 0; r < 4; ++r) {
      const int rg = orow + m * 16 + r;
      float rs = 0.f;
      #pragma unroll
      for (int n = 0; n < 4; ++n) {
        const int cg = ocol + n * 16;
        float p = (cg > rg) ? 0.0f : __expf(acc[m][n][r] * 0.03125f);
        rs += p;
        out[(long long)rg * 2048 + cg] = f2b(p);
      }
      #pragma unroll
      for (int off = 1; off < 16; off <<= 1) rs += __shfl_xor(rs, off);
      if ((lane & 15) == 0) atomicAdd(&sums[(long long)z * 2048 + rg], rs);
    }
}

// ==================== 128x128 2-phase PV (causal K-bound, XCD-grouped) ====================
// grid (x=stripe-sel 16, y=col 8, z=batch). id%8 = x%8 -> the 8 col-blocks of each
// stripe share one XCD (L2 reuse of the P stripe). Stripe pairing balances work:
// x<8 -> by=15-x (long, dispatched first), x>=8 -> by=x-8 (short); pair sums equal.
__global__ __launch_bounds__(256) void gemm_pv(
    const unsigned short* __restrict__ P, const unsigned short* __restrict__ Vt,
    float* __restrict__ out, const float* __restrict__ sums)
{
  const int z = blockIdx.z;
  const int sx = blockIdx.x;
  const int by = (sx < 8) ? (15 - sx) : (sx - 8);
  const int row0 = by * 128;
  const int col0 = blockIdx.y * 128;

  const unsigned short* Az = P + (long long)z * (2048 * 2048);
  const unsigned short* Bz = Vt + (long long)z * (1024 * 2048);

  __shared__ __align__(16) char lds[32768];

  const int tid = threadIdx.x;
  const int wave = tid >> 6;
  const int lane = tid & 63;
  const int wr = wave >> 1, wc = wave & 1;
  const int l15 = lane & 15, lk = lane >> 4;

  const int srow = lane >> 3;
  const int sgrp = (lane & 7) ^ srow;

  const int rA = wr * 64 + l15;
  const int cB = wc * 64 + l15;
  const int kb = lk * 16;
  const int xorA = (rA & 7) << 4;
  const int xorB = (cB & 7) << 4;

  f32x4 acc[4][4];
  #pragma unroll
  for (int m = 0; m < 4; ++m)
    #pragma unroll
    for (int n = 0; n < 4; ++n) acc[m][n] = (f32x4)0.0f;

  const int nkt = (row0 + 128) >> 6;

  for (int kt = 0; kt < nkt; ++kt) {
    const int kc = kt * 64;
    #pragma unroll
    for (int i = 0; i < 4; ++i) {
      const int ci = wave * 4 + i;
      gload16(Az + (long long)(row0 + ci * 8 + srow) * 2048 + kc + sgrp * 8,
              lds + ci * 1024);
      gload16(Bz + (long long)(col0 + ci * 8 + srow) * 2048 + kc + sgrp * 8,
              lds + 16384 + ci * 1024);
    }
    __syncthreads();
    #pragma unroll
    for (int ks = 0; ks < 2; ++ks) {
      short8 af[4], bfr[4];
      #pragma unroll
      for (int m = 0; m < 4; ++m)
        af[m] = *(const short8*)(lds + (rA + m * 16) * 128 + ((ks * 64 + kb) ^ xorA));
      #pragma unroll
      for (int n = 0; n < 4; ++n)
        bfr[n] = *(const short8*)(lds + 16384 + (cB + n * 16) * 128 + ((ks * 64 + kb) ^ xorB));
      #pragma unroll
      for (int m = 0; m < 4; ++m)
        #pragma unroll
        for (int n = 0; n < 4; ++n)
          acc[m][n] = __builtin_amdgcn_mfma_f32_16x16x32_bf16(af[m], bfr[n], acc[m][n], 0, 0, 0);
    }
    __syncthreads();
  }

  const int orow = row0 + wr * 64 + lk * 4;
  const int ocol = col0 + wc * 64 + l15;
  const float* sz = sums + (long long)z * 2048;
  float* oz = out + (long long)z * (2048 * 1024);
  #pragma unroll
  for (int m = 0; m < 4; ++m)
    #pragma unroll
    for (int r = 0; r < 4; ++r) {
      const int rg = orow + m * 16 + r;
      const float iv = 1.0f / sz[rg];
      #pragma unroll
      for (int n = 0; n < 4; ++n)
        oz[(long long)rg * 1024 + ocol + n * 16] = acc[m][n][r] * iv;
    }
}

extern "C" void kernel_launch(void* const* d_in, const int* in_sizes, int n_in,
                              void* d_out, int out_size, void* d_ws, size_t ws_size,
                              hipStream_t stream) {
  (void)in_sizes; (void)n_in; (void)out_size; (void)ws_size;
  const float* x  = (const float*)d_in[0];
  const float* Wq = (const float*)d_in[1];
  const float* Wk = (const float*)d_in[2];
  const float* Wv = (const float*)d_in[3];
  float* out = (float*)d_out;

  char* ws = (char*)d_ws;
  unsigned short* xb  = (unsigned short*)(ws);               // 8192x1024 bf16
  unsigned short* Wt2 = (unsigned short*)(ws + 16777216);    // [2048][1024]: M^T ; Wv^T
  unsigned short* y   = (unsigned short*)(ws + 20971520);    // 8192x1024 bf16
  unsigned short* Vt  = (unsigned short*)(ws + 37748736);    // 4x1024x2048 bf16
  unsigned short* P   = (unsigned short*)(ws + 54525952);    // 4x2048x2048 bf16
  float*          sums = (float*)(ws + 88080384);            // 4x2048 fp32

  // 1. prep: cvt x, transpose Wv, M^T = Wk.Wq^T, zero sums
  prep<<<9504, 256, 0, stream>>>(x, Wq, Wk, Wv, xb, Wt2, sums);

  // 2. [y | V] = x . [M^T ; Wv^T]^T  (256 gemm8 blocks, XCD-grouped rows)
  gemm8_yv<<<dim3(32, 8), 512, 0, stream>>>(xb, Wt2, y, Vt);

  // 3. P = exp((y x^T)/32) causal, unnormalized bf16 + rowsums
  gemm8_p<<<dim3(8, 8, 4), 512, 0, stream>>>(y, xb, P, sums);

  // 4. context = (P Vt^T)/rowsum  (128^2 2-phase, XCD-grouped stripes)
  gemm_pv<<<dim3(16, 8, 4), 256, 0, stream>>>(P, Vt, out, sums);
}